// Round 11
// baseline (191.585 us; speedup 1.0000x reference)
//
#include <hip/hip_runtime.h>

typedef unsigned int uint32;
typedef unsigned short u16;
typedef short s16x8 __attribute__((ext_vector_type(8)));
typedef short s16x4 __attribute__((ext_vector_type(4)));
typedef float f32x4 __attribute__((ext_vector_type(4)));

#define DEVINL static __device__ __forceinline__
#define MFMA16(a, b, c) __builtin_amdgcn_mfma_f32_16x16x32_bf16(a, b, c, 0, 0, 0)

DEVINL float bf2f(u16 u){ return __uint_as_float(((uint32)u) << 16); }
DEVINL u16 f2bf(float f){
  uint32 u = __float_as_uint(f);
  u += 0x7fffu + ((u >> 16) & 1u);   // RNE
  return (u16)(u >> 16);
}
DEVINL uint32 pack2(float a, float b){
  return (uint32)f2bf(a) | (((uint32)f2bf(b)) << 16);
}

// ---------------- dtype detector (proven) ----------------
__global__ void detect_k(const uint32* __restrict__ x, uint32* __restrict__ flag){
  const int lane = threadIdx.x;   // 64 threads
  int sane = 0;
  for (int i = 0; i < 32; ++i){
    uint32 u = x[i * 64 + lane];
    uint32 e = (u >> 7) & 0xffu;
    sane += (e >= 100u && e <= 150u) ? 1 : 0;
  }
  for (int off = 32; off >= 1; off >>= 1) sane += __shfl_xor(sane, off);
  if (lane == 0) *flag = (sane > 1024) ? 1u : 0u;   // 1 = bf16, 0 = fp32
}

// ---------------- all weights -> f32 blob (proven) ----------------
template<int M>
__global__ void cvtall_k(const void* s0, const void* s1, const void* s2,
                         const void* s3, const void* s4, const void* s5,
                         const void* s6, const void* s7, const void* s8,
                         float* __restrict__ wb, const uint32* __restrict__ flag)
{
  if (*flag != (uint32)M) return;
  const int i = blockIdx.x * 256 + threadIdx.x;
  if (i >= 196864) return;
  const void* s; int j;
  if      (i < 4096)   { s = s0; j = i; }
  else if (i < 8192)   { s = s1; j = i - 4096; }
  else if (i < 12288)  { s = s2; j = i - 8192; }
  else if (i < 49152)  { s = s3; j = i - 12288; }
  else if (i < 49216)  { s = s4; j = i - 49152; }
  else if (i < 122944) { s = s5; j = i - 49216; }
  else if (i < 123072) { s = s6; j = i - 122944; }
  else if (i < 196800) { s = s7; j = i - 123072; }
  else                 { s = s8; j = i - 196800; }
  wb[i] = M ? bf2f(((const u16*)s)[j]) : ((const float*)s)[j];
}

// ---------------- x -> bf16 convert (fp32 mode only) ----------------
__global__ __launch_bounds__(256)
void xcvt_k(const void* __restrict__ x, u16* __restrict__ xb,
            const uint32* __restrict__ flag)
{
  if (*flag != 0u) return;
  const size_t i0 = ((size_t)blockIdx.x * 256 + threadIdx.x) * 8;
  const float4 f0 = ((const float4*)x)[i0 / 4];
  const float4 f1 = ((const float4*)x)[i0 / 4 + 1];
  uint4 o;
  o.x = pack2(f0.x, f0.y); o.y = pack2(f0.z, f0.w);
  o.z = pack2(f1.x, f1.y); o.w = pack2(f1.z, f1.w);
  *(uint4*)(xb + i0) = o;
}

// ---------------- G = K_P @ Q_P^T -> hi/lo bf16 split ----------------
__global__ void gcomp_k(const float* __restrict__ wb, u16* __restrict__ gt){
  const int t = blockIdx.x * 256 + threadIdx.x;   // 4096
  const int d = t >> 6, c = t & 63;
  const float* __restrict__ K = wb + 4096;
  const float* __restrict__ Q = wb;
  float s = 0.f;
#pragma unroll
  for (int e = 0; e < 64; ++e) s = fmaf(K[d * 64 + e], Q[c * 64 + e], s);
  const u16 hi = f2bf(s);
  gt[t] = hi;
  gt[4096 + t] = f2bf(s - bf2f(hi));
}

// ---------------- pack vt(hi/lo) + K-chunked, bank-swizzled conv weights ----------------
// bb: gt[0,8192) vt[8192,12288) vlo[12288,16384) w1pk[16384,53248)
//     w2pk[53248,126976) w3pk[126976,200704)
__global__ void pack_k(const float* __restrict__ wb, u16* __restrict__ bb){
  int i = blockIdx.x * 256 + threadIdx.x;   // grid exact: 752*256 = 192512
  if (i < 4096){                                      // vt hi: vt[o][c] = V[c][o]
    const int o = i >> 6, c = i & 63;
    bb[8192 + i] = f2bf(wb[8192 + c * 64 + o]);
    return;
  }
  i -= 4096;
  if (i < 4096){                                      // vt lo
    const int o = i >> 6, c = i & 63;
    const float v = wb[8192 + c * 64 + o];
    bb[12288 + i] = f2bf(v - bf2f(f2bf(v)));
    return;
  }
  i -= 4096;
  if (i < 36864){                                     // w1pk (18 chunks)
    const int chunk = i >> 11, rr = i & 2047, co = rr >> 5, kkp = rr & 31;
    const int slot = (kkp >> 3) ^ ((co >> 1) & 3), kk = slot * 8 + (kkp & 7);
    const int tap = chunk >> 1, ci = (chunk & 1) * 32 + kk;
    bb[16384 + i] = f2bf(wb[12288 + (tap * 64 + ci) * 64 + co]);
    return;
  }
  i -= 36864;
  if (i < 73728){                                     // w2pk [2 halves][18 chunks]
    const int half = i / 36864, i2 = i - half * 36864;
    const int chunk = i2 >> 11, rr = i2 & 2047, co = rr >> 5, kkp = rr & 31;
    const int slot = (kkp >> 3) ^ ((co >> 1) & 3), kk = slot * 8 + (kkp & 7);
    const int tap = chunk >> 1, ci = (chunk & 1) * 32 + kk;
    bb[53248 + i] = f2bf(wb[49216 + (tap * 64 + ci) * 128 + half * 64 + co]);
    return;
  }
  i -= 73728;
  {                                                   // w3pk (36 chunks: tap*4 + ci_chunk)
    const int chunk = i >> 11, rr = i & 2047, co = rr >> 5, kkp = rr & 31;
    const int slot = (kkp >> 3) ^ ((co >> 1) & 3), kk = slot * 8 + (kkp & 7);
    const int tap = chunk >> 2, ci = (chunk & 3) * 32 + kk;
    bb[126976 + i] = f2bf(wb[123072 + (tap * 128 + ci) * 64 + co]);
  }
}

// ---------------- xv = x @ V (f32 out), V = vt_hi + vt_lo ----------------
__global__ __launch_bounds__(256)
void xv_k(const u16* __restrict__ xraw, const u16* __restrict__ xcv,
          const u16* __restrict__ vt, const u16* __restrict__ vlo,
          float* __restrict__ xv, const uint32* __restrict__ flag)
{
  const u16* __restrict__ xsrc = (*flag != 0u) ? xraw : xcv;
  const int bx0 = blockIdx.x;
  const int bx = (bx0 & 7) * 256 + (bx0 >> 3);       // match attn's XCD swizzle
  const int p0 = bx * 64;
  const int lane = threadIdx.x & 63, wv = threadIdx.x >> 6;
  const int l15 = lane & 15, lk = lane >> 4;

  f32x4 racc[4];
#pragma unroll
  for (int nt = 0; nt < 4; ++nt) racc[nt] = (f32x4){0.f, 0.f, 0.f, 0.f};
#pragma unroll
  for (int half = 0; half < 2; ++half){
    const u16* __restrict__ vb = half ? vlo : vt;
#pragma unroll
    for (int ks = 0; ks < 2; ++ks){
      const s16x8 af = *(const s16x8*)(xsrc +
          (size_t)(p0 + wv * 16 + l15) * 64 + ks * 32 + lk * 8);
#pragma unroll
      for (int nt = 0; nt < 4; ++nt){
        const s16x8 bf = *(const s16x8*)(vb + (size_t)(nt * 16 + l15) * 64 + ks * 32 + lk * 8);
        racc[nt] = MFMA16(af, bf, racc[nt]);
      }
    }
  }
#pragma unroll
  for (int nt = 0; nt < 4; ++nt)
#pragma unroll
    for (int reg = 0; reg < 4; ++reg)
      xv[(size_t)(p0 + wv * 16 + lk * 4 + reg) * 64 + nt * 16 + l15] = racc[nt][reg];
}

// ---------------- halo staging into swizzled LDS ----------------
// element ci of (row,col) lives at (row*66+col)*CIN + ((ci>>3)^(col&7))*8 + (ci&7)
template<int ROWS, int CIN, int STRIDE>
DEVINL void stage_tile(const u16* __restrict__ img_base, int h0, int w0, u16* lds){
  constexpr int CH8 = CIN / 8;
  constexpr int NCH = ROWS * 66 * CH8;
  for (int idx = threadIdx.x; idx < NCH; idx += 256){
    const int row  = idx / (66 * CH8);
    const int rem  = idx - row * 66 * CH8;
    const int col  = rem / CH8;
    const int slot = rem - col * CH8;
    const int hi = h0 + row - 1, wi = w0 + col - 1;
    uint4 v = make_uint4(0u, 0u, 0u, 0u);
    if (hi >= 0 && hi < 128 && wi >= 0 && wi < 128)
      v = *(const uint4*)(img_base + (size_t)(hi * 128 + wi) * STRIDE + slot * 8);
    const int dst = (row * 66 + col) * CIN + ((slot ^ (col & 7)) << 3);
    *(uint4*)(lds + dst) = v;
  }
}

// ---------------- fused 3x3 pixel attention (single-barrier form) ----------------
// QK with SWAPPED operands: mfma(G, x) -> lane owns r[d = nt*16+lk*4+reg][px = l15].
// Scores read x via ds_read_b64 at lane's own d-positions; reduce over lk via shfl.
// out = x + sum_n alpha_n * xv[p+off_n]  (xv f32, global/L3) -- no y pass, no PV.
__global__ __launch_bounds__(256, 4)
void attn_mfma(const u16* __restrict__ xraw, const u16* __restrict__ xcv,
               const u16* __restrict__ gt, const float* __restrict__ xv,
               u16* __restrict__ tb, const uint32* __restrict__ flag)
{
  __shared__ __align__(16) u16 xh[3 * 66 * 64];
  const int bx0 = blockIdx.x;
  const int bx = (bx0 & 7) * 256 + (bx0 >> 3);   // XCD-chunked swizzle (2048 wgs)
  const int img = bx >> 8, h = (bx >> 1) & 127, w0 = (bx & 1) * 64;
  const int p0 = img * 16384 + h * 128 + w0;
  const u16* __restrict__ xsrc = (*flag != 0u) ? xraw : xcv;
  stage_tile<3, 64, 64>(xsrc + (size_t)img * 16384 * 64, h, w0, xh);
  __syncthreads();   // the only barrier

  const int lane = threadIdx.x & 63, wv = threadIdx.x >> 6;
  const int l15 = lane & 15, lk = lane >> 4;
  const int pxm = wv * 16 + l15;          // block-local pixel this lane scores

  // ---- QK^T (swapped): racc[nt][reg] = r[d = nt*16+lk*4+reg][pxm] ----
  f32x4 racc[4];
#pragma unroll
  for (int nt = 0; nt < 4; ++nt) racc[nt] = (f32x4){0.f, 0.f, 0.f, 0.f};
#pragma unroll
  for (int half = 0; half < 2; ++half){
#pragma unroll
    for (int ks = 0; ks < 2; ++ks){
      const int colq = pxm + 1;
      const int slot = ks * 4 + lk;
      const s16x8 bx_ = *(const s16x8*)&xh[(66 + colq) * 64 + ((slot ^ (colq & 7)) << 3)];
#pragma unroll
      for (int nt = 0; nt < 4; ++nt){
        const s16x8 ag = *(const s16x8*)(gt + half * 4096 +
                          (size_t)(nt * 16 + l15) * 64 + ks * 32 + lk * 8);
        racc[nt] = MFMA16(ag, bx_, racc[nt]);
      }
    }
  }

  // ---- scores: s[n] = sum_d x[p+off_n][d] * r[d][p], lane sums its 16 d ----
  float sc[9];
#pragma unroll
  for (int n = 0; n < 9; ++n){
    const int tr = n / 3, tc = n % 3;
    const int col = pxm + tc;
    const u16* xr = &xh[(tr * 66 + col) * 64];
    float s = 0.f;
#pragma unroll
    for (int nt = 0; nt < 4; ++nt){
      const int slot = nt * 2 + (lk >> 1);
      const s16x4 v = *(const s16x4*)&xr[((slot ^ (col & 7)) << 3) + (lk & 1) * 4];
#pragma unroll
      for (int j = 0; j < 4; ++j)
        s = fmaf(bf2f((u16)v[j]), racc[nt][j], s);
    }
    sc[n] = s;
  }
#pragma unroll
  for (int n = 0; n < 9; ++n){
    sc[n] += __shfl_xor(sc[n], 16);
    sc[n] += __shfl_xor(sc[n], 32);
  }

  // ---- softmax over 9 (replicated across lk) ----
  float mx = sc[0];
#pragma unroll
  for (int n = 1; n < 9; ++n) mx = fmaxf(mx, sc[n]);
  float sum = 0.f;
#pragma unroll
  for (int n = 0; n < 9; ++n){
    const float e = __expf(sc[n] - mx);
    sc[n] = e; sum += e;
  }
  const float inv = 1.f / sum;
#pragma unroll
  for (int n = 0; n < 9; ++n) sc[n] *= inv;

  // ---- out[e in lk*16..+16] = x_own + sum_n alpha_n xv[p+off][e] ----
  float out[16];
#pragma unroll
  for (int sl = 0; sl < 2; ++sl){
    const int colq = pxm + 1;
    const int slot = lk * 2 + sl;
    const s16x8 v = *(const s16x8*)&xh[(66 + colq) * 64 + ((slot ^ (colq & 7)) << 3)];
#pragma unroll
    for (int j = 0; j < 8; ++j) out[sl * 8 + j] = bf2f((u16)v[j]);
  }
#pragma unroll
  for (int n = 0; n < 9; ++n){
    const int tr = n / 3, tc = n % 3;
    const int hh = h + tr - 1;
    const int wc = w0 + pxm + tc - 1;
    if (hh >= 0 && hh < 128 && wc >= 0 && wc < 128){
      const float a = sc[n];
      const float4* xp = (const float4*)(xv +
          (size_t)(img * 16384 + hh * 128 + wc) * 64 + lk * 16);
      const float4 v0 = xp[0], v1 = xp[1], v2 = xp[2], v3 = xp[3];
      out[0]  = fmaf(a, v0.x, out[0]);  out[1]  = fmaf(a, v0.y, out[1]);
      out[2]  = fmaf(a, v0.z, out[2]);  out[3]  = fmaf(a, v0.w, out[3]);
      out[4]  = fmaf(a, v1.x, out[4]);  out[5]  = fmaf(a, v1.y, out[5]);
      out[6]  = fmaf(a, v1.z, out[6]);  out[7]  = fmaf(a, v1.w, out[7]);
      out[8]  = fmaf(a, v2.x, out[8]);  out[9]  = fmaf(a, v2.y, out[9]);
      out[10] = fmaf(a, v2.z, out[10]); out[11] = fmaf(a, v2.w, out[11]);
      out[12] = fmaf(a, v3.x, out[12]); out[13] = fmaf(a, v3.y, out[13]);
      out[14] = fmaf(a, v3.z, out[14]); out[15] = fmaf(a, v3.w, out[15]);
    }
  }

  // ---- coalesced bf16 store: 32B per lane ----
  uint4 o0, o1;
  o0.x = pack2(out[0],  out[1]);  o0.y = pack2(out[2],  out[3]);
  o0.z = pack2(out[4],  out[5]);  o0.w = pack2(out[6],  out[7]);
  o1.x = pack2(out[8],  out[9]);  o1.y = pack2(out[10], out[11]);
  o1.z = pack2(out[12], out[13]); o1.w = pack2(out[14], out[15]);
  uint4* op = (uint4*)(tb + (size_t)(p0 + pxm) * 64 + lk * 16);
  op[0] = o0; op[1] = o1;
}

// ---------------- conv1/conv2 (CIN=64): MFMA implicit GEMM, TROWS=4, depth-2 B ----------------
template<int COUT_FULL, bool RES, int MOUT>
__global__ __launch_bounds__(256)
void conv_mfma(const u16* __restrict__ in, const u16* __restrict__ wpk,
               const float* __restrict__ bias, const u16* __restrict__ res,
               void* __restrict__ out, const uint32* __restrict__ flag)
{
  if (MOUT >= 0){ if (*flag != (uint32)MOUT) return; }
  constexpr int TOT = 18;
  __shared__ __align__(16) u16 xh[6 * 66 * 64];
  __shared__ __align__(16) u16 Bb[3][2048];

  const int bx0 = blockIdx.x;
  const int bx  = (bx0 & 7) * 64 + (bx0 >> 3);   // XCD-chunked swizzle (512 wgs)
  const int img = bx >> 6;
  const int rem = bx & 63;
  const int h0  = (rem >> 1) * 4;
  const int w0  = (rem & 1) * 64;
  const int co0 = blockIdx.y * 64;
  const u16* __restrict__ wp = wpk + (size_t)blockIdx.y * TOT * 2048;

  auto stageB = [&](int it, int buf){
    const char* g = (const char*)(wp + (size_t)it * 2048) + threadIdx.x * 16;
    char* l = (char*)&Bb[buf][0] + threadIdx.x * 16;
    __builtin_amdgcn_global_load_lds((const __attribute__((address_space(1))) void*)g,
                                     (__attribute__((address_space(3))) void*)l, 16, 0, 0);
  };

  stage_tile<6, 64, 64>(in + (size_t)img * 16384 * 64, h0, w0, xh);
  stageB(0, 0);
  stageB(1, 1);
  __syncthreads();   // full drain: halo + chunks 0,1 resident

  const int lane = threadIdx.x & 63, wv = threadIdx.x >> 6;
  const int l15 = lane & 15, lk = lane >> 4;

  f32x4 acc[4][4];
#pragma unroll
  for (int nt = 0; nt < 4; ++nt){
    const float b = bias[co0 + nt * 16 + l15];
#pragma unroll
    for (int at = 0; at < 4; ++at) acc[at][nt] = (f32x4){b, b, b, b};
  }

#pragma unroll 1
  for (int it = 0; it < TOT; ++it){
    if (it + 2 < TOT) stageB(it + 2, (it + 2) % 3);   // safe: that buf's readers
                                                      // finished before last barrier
    const int b = it % 3;
    const int tap = it >> 1, ks = it & 1;
    const int tr = tap / 3, tc = tap - tr * 3;
    const int slot = ks * 4 + lk;
    s16x8 av[4], bv[4];
#pragma unroll
    for (int at = 0; at < 4; ++at){
      const int col = at * 16 + l15 + tc;
      av[at] = *(const s16x8*)&xh[((wv + tr) * 66 + col) * 64 + ((slot ^ (col & 7)) << 3)];
    }
#pragma unroll
    for (int nt = 0; nt < 4; ++nt){
      const int co = nt * 16 + l15;
      bv[nt] = *(const s16x8*)&Bb[b][co * 32 + ((lk ^ ((co >> 1) & 3)) << 3)];
    }
#pragma unroll
    for (int at = 0; at < 4; ++at)
#pragma unroll
      for (int nt = 0; nt < 4; ++nt)
        acc[at][nt] = MFMA16(av[at], bv[nt], acc[at][nt]);

    if (it + 1 < TOT){
      if (it + 2 < TOT) asm volatile("s_waitcnt vmcnt(1)" ::: "memory");
      else              asm volatile("s_waitcnt vmcnt(0)" ::: "memory");
      __builtin_amdgcn_s_barrier();
      __builtin_amdgcn_sched_barrier(0);
    }
  }

#pragma unroll
  for (int at = 0; at < 4; ++at){
#pragma unroll
    for (int nt = 0; nt < 4; ++nt){
#pragma unroll
      for (int reg = 0; reg < 4; ++reg){
        float v = fmaxf(acc[at][nt][reg], 0.f);
        const int pxg = img * 16384 + (h0 + wv) * 128 + w0 + at * 16 + lk * 4 + reg;
        const int co  = co0 + nt * 16 + l15;
        const size_t oi = (size_t)pxg * COUT_FULL + co;
        if (RES) v += bf2f(res[oi]);
        if (MOUT == 0) ((float*)out)[oi] = v;
        else           ((u16*)out)[oi]   = f2bf(v);
      }
    }
  }
}

// ---------------- conv3 (CIN=128): TROWS=4, two-phase ci-half, depth-2 B ----------------
template<int MOUT>
__global__ __launch_bounds__(256)
void conv3_mfma(const u16* __restrict__ in, const u16* __restrict__ wpk,
                const float* __restrict__ bias, const u16* __restrict__ res,
                void* __restrict__ out, const uint32* __restrict__ flag)
{
  if (*flag != (uint32)MOUT) return;
  __shared__ __align__(16) u16 xh[6 * 66 * 64];
  __shared__ __align__(16) u16 Bb[3][2048];

  const int bx0 = blockIdx.x;
  const int bx  = (bx0 & 7) * 64 + (bx0 >> 3);   // XCD-chunked swizzle (512 wgs)
  const int img = bx >> 6;
  const int rem = bx & 63;
  const int h0  = (rem >> 1) * 4;
  const int w0  = (rem & 1) * 64;

  auto stageB = [&](int chunk, int buf){
    const char* g = (const char*)(wpk + (size_t)chunk * 2048) + threadIdx.x * 16;
    char* l = (char*)&Bb[buf][0] + threadIdx.x * 16;
    __builtin_amdgcn_global_load_lds((const __attribute__((address_space(1))) void*)g,
                                     (__attribute__((address_space(3))) void*)l, 16, 0, 0);
  };

  const int lane = threadIdx.x & 63, wv = threadIdx.x >> 6;
  const int l15 = lane & 15, lk = lane >> 4;

  auto chunkOf = [&](int it, int half){
    return ((it >> 1) << 2) + half * 2 + (it & 1);
  };

  f32x4 acc[4][4];
#pragma unroll
  for (int nt = 0; nt < 4; ++nt){
    const float b = bias[nt * 16 + l15];
#pragma unroll
    for (int at = 0; at < 4; ++at) acc[at][nt] = (f32x4){b, b, b, b};
  }

#pragma unroll 1
  for (int half = 0; half < 2; ++half){
    if (half) __syncthreads();   // all reads of phase-0 xh complete (MFMA dep + barrier)
    stage_tile<6, 64, 128>(in + (size_t)img * 16384 * 128 + half * 64, h0, w0, xh);
    stageB(chunkOf(0, half), 0);
    stageB(chunkOf(1, half), 1);
    __syncthreads();

#pragma unroll 1
    for (int it = 0; it < 18; ++it){
      if (it + 2 < 18) stageB(chunkOf(it + 2, half), (it + 2) % 3);
      const int b = it % 3;
      const int tap = it >> 1, ks2 = it & 1;
      const int tr = tap / 3, tc = tap - tr * 3;
      const int slot = ks2 * 4 + lk;
      s16x8 av[4], bv[4];
#pragma unroll
      for (int at = 0; at < 4; ++at){
        const int col = at * 16 + l15 + tc;
        av[at] = *(const s16x8*)&xh[((wv + tr) * 66 + col) * 64 + ((slot ^ (col & 7)) << 3)];
      }
#pragma unroll
      for (int nt = 0; nt < 4; ++nt){
        const int co = nt * 16 + l15;
        bv[nt] = *(const s16x8*)&Bb[b][co * 32 + ((lk ^ ((co >> 1) & 3)) << 3)];
      }
#pragma unroll
      for (int at = 0; at < 4; ++at)
#pragma unroll
        for (int nt = 0; nt < 4; ++nt)
          acc[at][nt] = MFMA16(av[at], bv[nt], acc[at][nt]);

      if (it + 1 < 18){
        if (it + 2 < 18) asm volatile("s_waitcnt vmcnt(1)" ::: "memory");
        else             asm volatile("s_waitcnt vmcnt(0)" ::: "memory");
        __builtin_amdgcn_s_barrier();
        __builtin_amdgcn_sched_barrier(0);
      }
    }
  }

#pragma unroll
  for (int at = 0; at < 4; ++at){
#pragma unroll
    for (int nt = 0; nt < 4; ++nt){
#pragma unroll
      for (int reg = 0; reg < 4; ++reg){
        float v = fmaxf(acc[at][nt][reg], 0.f);
        const int pxg = img * 16384 + (h0 + wv) * 128 + w0 + at * 16 + lk * 4 + reg;
        const int co  = nt * 16 + l15;
        const size_t oi = (size_t)pxg * 64 + co;
        v += bf2f(res[oi]);
        if (MOUT == 0) ((float*)out)[oi] = v;
        else           ((u16*)out)[oi]   = f2bf(v);
      }
    }
  }
}

extern "C" void kernel_launch(void* const* d_in, const int* in_sizes, int n_in,
                              void* d_out, int out_size, void* d_ws, size_t ws_size,
                              hipStream_t stream)
{
  (void)in_sizes; (void)n_in; (void)out_size; (void)ws_size;

  char* ws = (char*)d_ws;
  float*  wblob = (float*)ws;                            // 196864 f32
  uint32* flag  = (uint32*)(ws + 983040);
  u16*    bb    = (u16*)(ws + (1u << 20));               // bf16 blob (200704 u16)
  u16*    gt   = bb;                                     // [2][64][64] hi/lo
  u16*    vt   = bb + 8192;                              // [64][64] hi
  u16*    vlo  = bb + 12288;                             // [64][64] lo
  u16*    w1pk = bb + 16384;                             // 18 x 4KB chunks
  u16*    w2pk = bb + 53248;                             // 2 x 18 x 4KB
  u16*    w3pk = bb + 126976;                            // 36 x 4KB

  // buffer lifetimes: xv [2MB..35.55MB] dead after attn -> c2 reuses it;
  // xb [52.4MB..69.2MB] (fp32 mode only) dead after attn/xv -> c1 reuses it.
  float* xv = (float*)(ws + (size_t)2097152);            // 33.55 MB f32
  u16*   c2 = (u16*)(ws + (size_t)2097152);              // 33.55 MB (after attn)
  u16*   tb = (u16*)(ws + (size_t)35651584);             // 16.78 MB
  u16*   xb = (u16*)(ws + (size_t)52428800);             // 16.78 MB (fp32 mode)
  u16*   c1 = (u16*)(ws + (size_t)52428800);             // 16.78 MB (after attn)

  detect_k<<<1, 64, 0, stream>>>((const uint32*)d_in[0], flag);

  cvtall_k<0><<<769, 256, 0, stream>>>(d_in[1], d_in[2], d_in[3], d_in[4], d_in[5],
                                       d_in[6], d_in[7], d_in[8], d_in[9], wblob, flag);
  cvtall_k<1><<<769, 256, 0, stream>>>(d_in[1], d_in[2], d_in[3], d_in[4], d_in[5],
                                       d_in[6], d_in[7], d_in[8], d_in[9], wblob, flag);

  xcvt_k<<<4096, 256, 0, stream>>>(d_in[0], xb, flag);   // fp32 mode only

  gcomp_k<<<16, 256, 0, stream>>>(wblob, gt);
  pack_k<<<752, 256, 0, stream>>>(wblob, bb);

  xv_k<<<2048, 256, 0, stream>>>((const u16*)d_in[0], xb, vt, vlo, xv, flag);

  attn_mfma<<<2048, 256, 0, stream>>>((const u16*)d_in[0], xb, gt, xv, tb, flag);

  conv_mfma<64, false, -1><<<dim3(512, 1), 256, 0, stream>>>(
      tb, w1pk, wblob + 49152, nullptr, c1, flag);
  conv_mfma<128, false, -1><<<dim3(512, 2), 256, 0, stream>>>(
      c1, w2pk, wblob + 122944, nullptr, c2, flag);
  conv3_mfma<0><<<512, 256, 0, stream>>>(
      c2, w3pk, wblob + 196800, tb, d_out, flag);
  conv3_mfma<1><<<512, 256, 0, stream>>>(
      c2, w3pk, wblob + 196800, tb, d_out, flag);
}

// Round 12
// 150.565 us; speedup vs baseline: 1.2724x; 1.2724x over previous
//
#include <hip/hip_runtime.h>

typedef unsigned int uint32;
typedef unsigned short u16;
typedef short s16x8 __attribute__((ext_vector_type(8)));
typedef short s16x4 __attribute__((ext_vector_type(4)));
typedef float f32x4 __attribute__((ext_vector_type(4)));

#define DEVINL static __device__ __forceinline__
#define MFMA16(a, b, c) __builtin_amdgcn_mfma_f32_16x16x32_bf16(a, b, c, 0, 0, 0)

DEVINL float bf2f(u16 u){ return __uint_as_float(((uint32)u) << 16); }
DEVINL u16 f2bf(float f){
  uint32 u = __float_as_uint(f);
  u += 0x7fffu + ((u >> 16) & 1u);   // RNE
  return (u16)(u >> 16);
}
DEVINL uint32 pack2(float a, float b){
  return (uint32)f2bf(a) | (((uint32)f2bf(b)) << 16);
}

// ---------------- dtype detector (proven) ----------------
__global__ void detect_k(const uint32* __restrict__ x, uint32* __restrict__ flag){
  const int lane = threadIdx.x;   // 64 threads
  int sane = 0;
  for (int i = 0; i < 32; ++i){
    uint32 u = x[i * 64 + lane];
    uint32 e = (u >> 7) & 0xffu;
    sane += (e >= 100u && e <= 150u) ? 1 : 0;
  }
  for (int off = 32; off >= 1; off >>= 1) sane += __shfl_xor(sane, off);
  if (lane == 0) *flag = (sane > 1024) ? 1u : 0u;   // 1 = bf16, 0 = fp32
}

// ---------------- all weights -> f32 blob (proven) ----------------
template<int M>
__global__ void cvtall_k(const void* s0, const void* s1, const void* s2,
                         const void* s3, const void* s4, const void* s5,
                         const void* s6, const void* s7, const void* s8,
                         float* __restrict__ wb, const uint32* __restrict__ flag)
{
  if (*flag != (uint32)M) return;
  const int i = blockIdx.x * 256 + threadIdx.x;
  if (i >= 196864) return;
  const void* s; int j;
  if      (i < 4096)   { s = s0; j = i; }
  else if (i < 8192)   { s = s1; j = i - 4096; }
  else if (i < 12288)  { s = s2; j = i - 8192; }
  else if (i < 49152)  { s = s3; j = i - 12288; }
  else if (i < 49216)  { s = s4; j = i - 49152; }
  else if (i < 122944) { s = s5; j = i - 49216; }
  else if (i < 123072) { s = s6; j = i - 122944; }
  else if (i < 196800) { s = s7; j = i - 123072; }
  else                 { s = s8; j = i - 196800; }
  wb[i] = M ? bf2f(((const u16*)s)[j]) : ((const float*)s)[j];
}

// ---------------- x -> bf16 convert (fp32 mode only) ----------------
__global__ __launch_bounds__(256)
void xcvt_k(const void* __restrict__ x, u16* __restrict__ xb,
            const uint32* __restrict__ flag)
{
  if (*flag != 0u) return;
  const size_t i0 = ((size_t)blockIdx.x * 256 + threadIdx.x) * 8;
  const float4 f0 = ((const float4*)x)[i0 / 4];
  const float4 f1 = ((const float4*)x)[i0 / 4 + 1];
  uint4 o;
  o.x = pack2(f0.x, f0.y); o.y = pack2(f0.z, f0.w);
  o.z = pack2(f1.x, f1.y); o.w = pack2(f1.z, f1.w);
  *(uint4*)(xb + i0) = o;
}

// ---------------- G = K_P @ Q_P^T -> hi/lo bf16 split ----------------
__global__ void gcomp_k(const float* __restrict__ wb, u16* __restrict__ gt){
  const int t = blockIdx.x * 256 + threadIdx.x;   // 4096
  const int d = t >> 6, c = t & 63;
  const float* __restrict__ K = wb + 4096;
  const float* __restrict__ Q = wb;
  float s = 0.f;
#pragma unroll
  for (int e = 0; e < 64; ++e) s = fmaf(K[d * 64 + e], Q[c * 64 + e], s);
  const u16 hi = f2bf(s);
  gt[t] = hi;
  gt[4096 + t] = f2bf(s - bf2f(hi));
}

// ---------------- pack vt(hi/lo) + K-chunked, bank-swizzled conv weights ----------------
// bb: gt[0,8192) vt[8192,12288) vlo[12288,16384) w1pk[16384,53248)
//     w2pk[53248,126976) w3pk[126976,200704)
__global__ void pack_k(const float* __restrict__ wb, u16* __restrict__ bb){
  int i = blockIdx.x * 256 + threadIdx.x;   // grid exact: 752*256 = 192512
  if (i < 4096){                                      // vt hi: vt[o][c] = V[c][o]
    const int o = i >> 6, c = i & 63;
    bb[8192 + i] = f2bf(wb[8192 + c * 64 + o]);
    return;
  }
  i -= 4096;
  if (i < 4096){                                      // vt lo (kept, unused this round)
    const int o = i >> 6, c = i & 63;
    const float v = wb[8192 + c * 64 + o];
    bb[12288 + i] = f2bf(v - bf2f(f2bf(v)));
    return;
  }
  i -= 4096;
  if (i < 36864){                                     // w1pk (18 chunks)
    const int chunk = i >> 11, rr = i & 2047, co = rr >> 5, kkp = rr & 31;
    const int slot = (kkp >> 3) ^ ((co >> 1) & 3), kk = slot * 8 + (kkp & 7);
    const int tap = chunk >> 1, ci = (chunk & 1) * 32 + kk;
    bb[16384 + i] = f2bf(wb[12288 + (tap * 64 + ci) * 64 + co]);
    return;
  }
  i -= 36864;
  if (i < 73728){                                     // w2pk [2 halves][18 chunks]
    const int half = i / 36864, i2 = i - half * 36864;
    const int chunk = i2 >> 11, rr = i2 & 2047, co = rr >> 5, kkp = rr & 31;
    const int slot = (kkp >> 3) ^ ((co >> 1) & 3), kk = slot * 8 + (kkp & 7);
    const int tap = chunk >> 1, ci = (chunk & 1) * 32 + kk;
    bb[53248 + i] = f2bf(wb[49216 + (tap * 64 + ci) * 128 + half * 64 + co]);
    return;
  }
  i -= 73728;
  {                                                   // w3pk (36 chunks: tap*4 + ci_chunk)
    const int chunk = i >> 11, rr = i & 2047, co = rr >> 5, kkp = rr & 31;
    const int slot = (kkp >> 3) ^ ((co >> 1) & 3), kk = slot * 8 + (kkp & 7);
    const int tap = chunk >> 2, ci = (chunk & 3) * 32 + kk;
    bb[126976 + i] = f2bf(wb[123072 + (tap * 128 + ci) * 64 + co]);
  }
}

// ---------------- halo staging into swizzled LDS ----------------
// element ci of (row,col) lives at (row*66+col)*CIN + ((ci>>3)^(col&7))*8 + (ci&7)
template<int ROWS, int CIN, int STRIDE>
DEVINL void stage_tile(const u16* __restrict__ img_base, int h0, int w0, u16* lds){
  constexpr int CH8 = CIN / 8;
  constexpr int NCH = ROWS * 66 * CH8;
  for (int idx = threadIdx.x; idx < NCH; idx += 256){
    const int row  = idx / (66 * CH8);
    const int rem  = idx - row * 66 * CH8;
    const int col  = rem / CH8;
    const int slot = rem - col * CH8;
    const int hi = h0 + row - 1, wi = w0 + col - 1;
    uint4 v = make_uint4(0u, 0u, 0u, 0u);
    if (hi >= 0 && hi < 128 && wi >= 0 && wi < 128)
      v = *(const uint4*)(img_base + (size_t)(hi * 128 + wi) * STRIDE + slot * 8);
    const int dst = (row * 66 + col) * CIN + ((slot ^ (col & 7)) << 3);
    *(uint4*)(lds + dst) = v;
  }
}

// ---------------- fused 3x3 pixel attention (hybrid r10/r11) ----------------
// QK with SWAPPED operands (r11, proven): lane owns r[d = nt*16+lk*4+reg][px = l15]
// -> no rl transpose, no extra barrier. Scores via 36 ds_read_b64 + 2 shfl.
// y + PV via LDS (r10, proven): y hi/lo into dead halo rows 0/2, PV MFMA with vt.
// Barriers: sync1 stage; sync3 rows-0/2 reads done before alias writes; sync4
// writes visible before PV reads (round-8 race lesson).
__global__ __launch_bounds__(256, 4)
void attn_mfma(const u16* __restrict__ xraw, const u16* __restrict__ xcv,
               const u16* __restrict__ gt, const u16* __restrict__ vt,
               u16* __restrict__ tb, const uint32* __restrict__ flag)
{
  __shared__ __align__(16) u16 xh[3 * 66 * 64];
  u16* yl  = xh;                   // aliases halo row 0
  u16* yl2 = xh + 2 * 66 * 64;     // aliases halo row 2
  const int bx0 = blockIdx.x;
  const int bx = (bx0 & 7) * 256 + (bx0 >> 3);   // XCD-chunked swizzle (2048 wgs)
  const int img = bx >> 8, h = (bx >> 1) & 127, w0 = (bx & 1) * 64;
  const int p0 = img * 16384 + h * 128 + w0;
  const u16* __restrict__ xsrc = (*flag != 0u) ? xraw : xcv;
  stage_tile<3, 64, 64>(xsrc + (size_t)img * 16384 * 64, h, w0, xh);
  __syncthreads();   // sync1

  const int lane = threadIdx.x & 63, wv = threadIdx.x >> 6;
  const int l15 = lane & 15, lk = lane >> 4;
  const int pxm = wv * 16 + l15;          // block-local pixel this lane scores

  // ---- QK^T (swapped): racc[nt][reg] = r[d = nt*16+lk*4+reg][pxm] ----
  f32x4 racc[4];
#pragma unroll
  for (int nt = 0; nt < 4; ++nt) racc[nt] = (f32x4){0.f, 0.f, 0.f, 0.f};
#pragma unroll
  for (int half = 0; half < 2; ++half){
#pragma unroll
    for (int ks = 0; ks < 2; ++ks){
      const int colq = pxm + 1;
      const int slot = ks * 4 + lk;
      const s16x8 bx_ = *(const s16x8*)&xh[(66 + colq) * 64 + ((slot ^ (colq & 7)) << 3)];
#pragma unroll
      for (int nt = 0; nt < 4; ++nt){
        const s16x8 ag = *(const s16x8*)(gt + half * 4096 +
                          (size_t)(nt * 16 + l15) * 64 + ks * 32 + lk * 8);
        racc[nt] = MFMA16(ag, bx_, racc[nt]);
      }
    }
  }

  // ---- scores: s[n] = sum_d x[p+off_n][d] * r[d][p], lane sums its 16 d ----
  float sc[9];
#pragma unroll
  for (int n = 0; n < 9; ++n){
    const int tr = n / 3, tc = n % 3;
    const int col = pxm + tc;
    const u16* xr = &xh[(tr * 66 + col) * 64];
    float s = 0.f;
#pragma unroll
    for (int nt = 0; nt < 4; ++nt){
      const int slot = nt * 2 + (lk >> 1);
      const s16x4 v = *(const s16x4*)&xr[((slot ^ (col & 7)) << 3) + (lk & 1) * 4];
#pragma unroll
      for (int j = 0; j < 4; ++j)
        s = fmaf(bf2f((u16)v[j]), racc[nt][j], s);
    }
    sc[n] = s;
  }
#pragma unroll
  for (int n = 0; n < 9; ++n){
    sc[n] += __shfl_xor(sc[n], 16);
    sc[n] += __shfl_xor(sc[n], 32);
  }

  // ---- softmax over 9 (replicated across lk) ----
  float mx = sc[0];
#pragma unroll
  for (int n = 1; n < 9; ++n) mx = fmaxf(mx, sc[n]);
  float sum = 0.f;
#pragma unroll
  for (int n = 0; n < 9; ++n){
    const float e = __expf(sc[n] - mx);
    sc[n] = e; sum += e;
  }
  const float inv = 1.f / sum;
#pragma unroll
  for (int n = 0; n < 9; ++n) sc[n] *= inv;

  // ---- y[e in lk*16..+16] = sum_n alpha_n x_n[e]  (all reads from LDS) ----
  float y[16];
#pragma unroll
  for (int j = 0; j < 16; ++j) y[j] = 0.f;
#pragma unroll
  for (int n = 0; n < 9; ++n){
    const int tr = n / 3, tc = n % 3;
    const int col = pxm + tc;
    const u16* xr = &xh[(tr * 66 + col) * 64];
    const float a = sc[n];
#pragma unroll
    for (int sl = 0; sl < 2; ++sl){
      const int slot = lk * 2 + sl;
      const s16x8 v = *(const s16x8*)&xr[(slot ^ (col & 7)) << 3];
#pragma unroll
      for (int j = 0; j < 8; ++j)
        y[sl * 8 + j] = fmaf(a, bf2f((u16)v[j]), y[sl * 8 + j]);
    }
  }

  __syncthreads();   // sync3: all xh row-0/2 reads complete before alias writes

#pragma unroll
  for (int sl = 0; sl < 2; ++sl){
    uint32 hwd[4], lwd[4];
#pragma unroll
    for (int j = 0; j < 4; ++j){
      const float a = y[sl * 8 + 2 * j], b = y[sl * 8 + 2 * j + 1];
      const u16 ha = f2bf(a), hb = f2bf(b);
      hwd[j] = (uint32)ha | ((uint32)hb << 16);
      lwd[j] = (uint32)f2bf(a - bf2f(ha)) | ((uint32)f2bf(b - bf2f(hb)) << 16);
    }
    const int slot = lk * 2 + sl;
    const int off = pxm * 64 + ((slot ^ (pxm & 7)) << 3);
    *(uint4*)&yl [off] = make_uint4(hwd[0], hwd[1], hwd[2], hwd[3]);
    *(uint4*)&yl2[off] = make_uint4(lwd[0], lwd[1], lwd[2], lwd[3]);
  }

  __syncthreads();   // sync4: y visible before PV reads

  // ---- PV: t = x + (yhi + ylo) @ V ----
  f32x4 tacc[4];
#pragma unroll
  for (int nt = 0; nt < 4; ++nt) tacc[nt] = (f32x4){0.f, 0.f, 0.f, 0.f};
#pragma unroll
  for (int half = 0; half < 2; ++half){
    const u16* yb = half ? yl2 : yl;
#pragma unroll
    for (int ks = 0; ks < 2; ++ks){
      const int px = wv * 16 + l15;
      const int slot = ks * 4 + lk;
      const s16x8 af = *(const s16x8*)&yb[px * 64 + ((slot ^ (px & 7)) << 3)];
#pragma unroll
      for (int nt = 0; nt < 4; ++nt){
        const s16x8 bf = *(const s16x8*)(vt + (size_t)(nt * 16 + l15) * 64 + ks * 32 + lk * 8);
        tacc[nt] = MFMA16(af, bf, tacc[nt]);
      }
    }
  }
#pragma unroll
  for (int nt = 0; nt < 4; ++nt){
#pragma unroll
    for (int reg = 0; reg < 4; ++reg){
      const int pxo = wv * 16 + lk * 4 + reg;
      const int co = nt * 16 + l15;
      const int col = pxo + 1;
      const int elem = (66 + col) * 64 + (((co >> 3) ^ (col & 7)) << 3) + (co & 7);
      tb[(size_t)(p0 + pxo) * 64 + co] = f2bf(bf2f(xh[elem]) + tacc[nt][reg]);
    }
  }
}

// ---------------- conv1/conv2 (CIN=64): MFMA implicit GEMM, TROWS=4, depth-2 B ----------------
template<int COUT_FULL, bool RES, int MOUT>
__global__ __launch_bounds__(256)
void conv_mfma(const u16* __restrict__ in, const u16* __restrict__ wpk,
               const float* __restrict__ bias, const u16* __restrict__ res,
               void* __restrict__ out, const uint32* __restrict__ flag)
{
  if (MOUT >= 0){ if (*flag != (uint32)MOUT) return; }
  constexpr int TOT = 18;
  __shared__ __align__(16) u16 xh[6 * 66 * 64];
  __shared__ __align__(16) u16 Bb[3][2048];

  const int bx0 = blockIdx.x;
  const int bx  = (bx0 & 7) * 64 + (bx0 >> 3);   // XCD-chunked swizzle (512 wgs)
  const int img = bx >> 6;
  const int rem = bx & 63;
  const int h0  = (rem >> 1) * 4;
  const int w0  = (rem & 1) * 64;
  const int co0 = blockIdx.y * 64;
  const u16* __restrict__ wp = wpk + (size_t)blockIdx.y * TOT * 2048;

  auto stageB = [&](int it, int buf){
    const char* g = (const char*)(wp + (size_t)it * 2048) + threadIdx.x * 16;
    char* l = (char*)&Bb[buf][0] + threadIdx.x * 16;
    __builtin_amdgcn_global_load_lds((const __attribute__((address_space(1))) void*)g,
                                     (__attribute__((address_space(3))) void*)l, 16, 0, 0);
  };

  stage_tile<6, 64, 64>(in + (size_t)img * 16384 * 64, h0, w0, xh);
  stageB(0, 0);
  stageB(1, 1);
  __syncthreads();   // full drain: halo + chunks 0,1 resident

  const int lane = threadIdx.x & 63, wv = threadIdx.x >> 6;
  const int l15 = lane & 15, lk = lane >> 4;

  f32x4 acc[4][4];
#pragma unroll
  for (int nt = 0; nt < 4; ++nt){
    const float b = bias[co0 + nt * 16 + l15];
#pragma unroll
    for (int at = 0; at < 4; ++at) acc[at][nt] = (f32x4){b, b, b, b};
  }

#pragma unroll 1
  for (int it = 0; it < TOT; ++it){
    if (it + 2 < TOT) stageB(it + 2, (it + 2) % 3);   // safe: that buf's readers
                                                      // finished before last barrier
    const int b = it % 3;
    const int tap = it >> 1, ks = it & 1;
    const int tr = tap / 3, tc = tap - tr * 3;
    const int slot = ks * 4 + lk;
    s16x8 av[4], bv[4];
#pragma unroll
    for (int at = 0; at < 4; ++at){
      const int col = at * 16 + l15 + tc;
      av[at] = *(const s16x8*)&xh[((wv + tr) * 66 + col) * 64 + ((slot ^ (col & 7)) << 3)];
    }
#pragma unroll
    for (int nt = 0; nt < 4; ++nt){
      const int co = nt * 16 + l15;
      bv[nt] = *(const s16x8*)&Bb[b][co * 32 + ((lk ^ ((co >> 1) & 3)) << 3)];
    }
#pragma unroll
    for (int at = 0; at < 4; ++at)
#pragma unroll
      for (int nt = 0; nt < 4; ++nt)
        acc[at][nt] = MFMA16(av[at], bv[nt], acc[at][nt]);

    if (it + 1 < TOT){
      if (it + 2 < TOT) asm volatile("s_waitcnt vmcnt(1)" ::: "memory");
      else              asm volatile("s_waitcnt vmcnt(0)" ::: "memory");
      __builtin_amdgcn_s_barrier();
      __builtin_amdgcn_sched_barrier(0);
    }
  }

#pragma unroll
  for (int at = 0; at < 4; ++at){
#pragma unroll
    for (int nt = 0; nt < 4; ++nt){
#pragma unroll
      for (int reg = 0; reg < 4; ++reg){
        float v = fmaxf(acc[at][nt][reg], 0.f);
        const int pxg = img * 16384 + (h0 + wv) * 128 + w0 + at * 16 + lk * 4 + reg;
        const int co  = co0 + nt * 16 + l15;
        const size_t oi = (size_t)pxg * COUT_FULL + co;
        if (RES) v += bf2f(res[oi]);
        if (MOUT == 0) ((float*)out)[oi] = v;
        else           ((u16*)out)[oi]   = f2bf(v);
      }
    }
  }
}

// ---------------- conv3 (CIN=128): TROWS=4, two-phase ci-half, depth-2 B ----------------
template<int MOUT>
__global__ __launch_bounds__(256)
void conv3_mfma(const u16* __restrict__ in, const u16* __restrict__ wpk,
                const float* __restrict__ bias, const u16* __restrict__ res,
                void* __restrict__ out, const uint32* __restrict__ flag)
{
  if (*flag != (uint32)MOUT) return;
  __shared__ __align__(16) u16 xh[6 * 66 * 64];
  __shared__ __align__(16) u16 Bb[3][2048];

  const int bx0 = blockIdx.x;
  const int bx  = (bx0 & 7) * 64 + (bx0 >> 3);   // XCD-chunked swizzle (512 wgs)
  const int img = bx >> 6;
  const int rem = bx & 63;
  const int h0  = (rem >> 1) * 4;
  const int w0  = (rem & 1) * 64;

  auto stageB = [&](int chunk, int buf){
    const char* g = (const char*)(wpk + (size_t)chunk * 2048) + threadIdx.x * 16;
    char* l = (char*)&Bb[buf][0] + threadIdx.x * 16;
    __builtin_amdgcn_global_load_lds((const __attribute__((address_space(1))) void*)g,
                                     (__attribute__((address_space(3))) void*)l, 16, 0, 0);
  };

  const int lane = threadIdx.x & 63, wv = threadIdx.x >> 6;
  const int l15 = lane & 15, lk = lane >> 4;

  auto chunkOf = [&](int it, int half){
    return ((it >> 1) << 2) + half * 2 + (it & 1);
  };

  f32x4 acc[4][4];
#pragma unroll
  for (int nt = 0; nt < 4; ++nt){
    const float b = bias[nt * 16 + l15];
#pragma unroll
    for (int at = 0; at < 4; ++at) acc[at][nt] = (f32x4){b, b, b, b};
  }

#pragma unroll 1
  for (int half = 0; half < 2; ++half){
    if (half) __syncthreads();   // all reads of phase-0 xh complete
    stage_tile<6, 64, 128>(in + (size_t)img * 16384 * 128 + half * 64, h0, w0, xh);
    stageB(chunkOf(0, half), 0);
    stageB(chunkOf(1, half), 1);
    __syncthreads();

#pragma unroll 1
    for (int it = 0; it < 18; ++it){
      if (it + 2 < 18) stageB(chunkOf(it + 2, half), (it + 2) % 3);
      const int b = it % 3;
      const int tap = it >> 1, ks2 = it & 1;
      const int tr = tap / 3, tc = tap - tr * 3;
      const int slot = ks2 * 4 + lk;
      s16x8 av[4], bv[4];
#pragma unroll
      for (int at = 0; at < 4; ++at){
        const int col = at * 16 + l15 + tc;
        av[at] = *(const s16x8*)&xh[((wv + tr) * 66 + col) * 64 + ((slot ^ (col & 7)) << 3)];
      }
#pragma unroll
      for (int nt = 0; nt < 4; ++nt){
        const int co = nt * 16 + l15;
        bv[nt] = *(const s16x8*)&Bb[b][co * 32 + ((lk ^ ((co >> 1) & 3)) << 3)];
      }
#pragma unroll
      for (int at = 0; at < 4; ++at)
#pragma unroll
        for (int nt = 0; nt < 4; ++nt)
          acc[at][nt] = MFMA16(av[at], bv[nt], acc[at][nt]);

      if (it + 1 < 18){
        if (it + 2 < 18) asm volatile("s_waitcnt vmcnt(1)" ::: "memory");
        else             asm volatile("s_waitcnt vmcnt(0)" ::: "memory");
        __builtin_amdgcn_s_barrier();
        __builtin_amdgcn_sched_barrier(0);
      }
    }
  }

#pragma unroll
  for (int at = 0; at < 4; ++at){
#pragma unroll
    for (int nt = 0; nt < 4; ++nt){
#pragma unroll
      for (int reg = 0; reg < 4; ++reg){
        float v = fmaxf(acc[at][nt][reg], 0.f);
        const int pxg = img * 16384 + (h0 + wv) * 128 + w0 + at * 16 + lk * 4 + reg;
        const int co  = nt * 16 + l15;
        const size_t oi = (size_t)pxg * 64 + co;
        v += bf2f(res[oi]);
        if (MOUT == 0) ((float*)out)[oi] = v;
        else           ((u16*)out)[oi]   = f2bf(v);
      }
    }
  }
}

extern "C" void kernel_launch(void* const* d_in, const int* in_sizes, int n_in,
                              void* d_out, int out_size, void* d_ws, size_t ws_size,
                              hipStream_t stream)
{
  (void)in_sizes; (void)n_in; (void)out_size; (void)ws_size;

  char* ws = (char*)d_ws;
  float*  wblob = (float*)ws;                            // 196864 f32
  uint32* flag  = (uint32*)(ws + 983040);
  u16*    bb    = (u16*)(ws + (1u << 20));               // bf16 blob (200704 u16)
  u16*    gt   = bb;                                     // [2][64][64] hi/lo
  u16*    vt   = bb + 8192;                              // [64][64] hi
  u16*    w1pk = bb + 16384;                             // 18 x 4KB chunks
  u16*    w2pk = bb + 53248;                             // 2 x 18 x 4KB
  u16*    w3pk = bb + 126976;                            // 36 x 4KB

  u16*   c2 = (u16*)(ws + (size_t)2097152);              // 33.55 MB
  u16*   tb = (u16*)(ws + (size_t)35651584);             // 16.78 MB
  u16*   xb = (u16*)(ws + (size_t)52428800);             // 16.78 MB (fp32 mode)
  u16*   c1 = (u16*)(ws + (size_t)52428800);             // 16.78 MB (after attn)

  detect_k<<<1, 64, 0, stream>>>((const uint32*)d_in[0], flag);

  cvtall_k<0><<<769, 256, 0, stream>>>(d_in[1], d_in[2], d_in[3], d_in[4], d_in[5],
                                       d_in[6], d_in[7], d_in[8], d_in[9], wblob, flag);
  cvtall_k<1><<<769, 256, 0, stream>>>(d_in[1], d_in[2], d_in[3], d_in[4], d_in[5],
                                       d_in[6], d_in[7], d_in[8], d_in[9], wblob, flag);

  xcvt_k<<<4096, 256, 0, stream>>>(d_in[0], xb, flag);   // fp32 mode only

  gcomp_k<<<16, 256, 0, stream>>>(wblob, gt);
  pack_k<<<752, 256, 0, stream>>>(wblob, bb);

  attn_mfma<<<2048, 256, 0, stream>>>((const u16*)d_in[0], xb, gt, vt, tb, flag);

  conv_mfma<64, false, -1><<<dim3(512, 1), 256, 0, stream>>>(
      tb, w1pk, wblob + 49152, nullptr, c1, flag);
  conv_mfma<128, false, -1><<<dim3(512, 2), 256, 0, stream>>>(
      c1, w2pk, wblob + 122944, nullptr, c2, flag);
  conv3_mfma<0><<<512, 256, 0, stream>>>(
      c2, w3pk, wblob + 196800, tb, d_out, flag);
  conv3_mfma<1><<<512, 256, 0, stream>>>(
      c2, w3pk, wblob + 196800, tb, d_out, flag);
}